// Round 8
// baseline (690.397 us; speedup 1.0000x reference)
//
#include <hip/hip_runtime.h>
#include <hip/hip_bf16.h>
#include <math.h>

typedef __hip_bfloat16 bf16;
typedef __attribute__((ext_vector_type(8))) short short8;
typedef __attribute__((ext_vector_type(4))) float float4_;
typedef __attribute__((ext_vector_type(4))) unsigned short ushort4_;

#define B_   2
#define T_   2048
#define D_   1024
#define H_   16
#define NTOK (B_ * T_)
#define NEG_SENT -1e30f

#define AS1 __attribute__((address_space(1)))
#define AS3 __attribute__((address_space(3)))

static __device__ __forceinline__ float b2f(bf16 v) { return __bfloat162float(v); }
static __device__ __forceinline__ bf16  f2b(float v) { return __float2bfloat16(v); }
static __device__ __forceinline__ unsigned short f2s(float v) {  // fp32 -> bf16 bits (RNE)
    unsigned u = __builtin_bit_cast(unsigned, v);
    unsigned r = (u + 0x7FFFu + ((u >> 16) & 1u)) >> 16;
    return (unsigned short)r;
}
static __device__ __forceinline__ float to_f(float v) { return v; }
static __device__ __forceinline__ float to_f(bf16 v) { return __bfloat162float(v); }
static __device__ __forceinline__ void  store_o(float* p, float v) { *p = v; }
static __device__ __forceinline__ void  store_o(bf16* p, float v) { *p = __float2bfloat16(v); }
static __device__ __forceinline__ void gl_lds16(const void* g, void* l) {
    __builtin_amdgcn_global_load_lds((const AS1 unsigned int*)g, (AS3 unsigned int*)l, 16, 0, 0);
}

// ---------------- RMSNorm over D=1024 (one block per token), fp32 in, bf16 out
__global__ __launch_bounds__(256) void rmsnorm_k(const float* __restrict__ x,
                                                 const float* __restrict__ w,
                                                 bf16* __restrict__ out) {
    int t = blockIdx.x, tid = threadIdx.x;
    float xs[4], ss = 0.f;
#pragma unroll
    for (int i = 0; i < 4; ++i) {
        float v = x[(size_t)t * D_ + tid + i * 256];
        xs[i] = v; ss += v * v;
    }
    __shared__ float red[4];
#pragma unroll
    for (int off = 32; off > 0; off >>= 1) ss += __shfl_xor(ss, off, 64);
    if ((tid & 63) == 0) red[tid >> 6] = ss;
    __syncthreads();
    ss = red[0] + red[1] + red[2] + red[3];
    float inv = rsqrtf(ss * (1.f / D_) + 1e-6f);
#pragma unroll
    for (int i = 0; i < 4; ++i) {
        int c = tid + i * 256;
        out[(size_t)t * D_ + c] = f2b(xs[i] * inv * w[c]);
    }
}

// ------- fused modulate (x = x*(1+scale1)+shift1, in place fp32) + RMSNorm2 --
__global__ __launch_bounds__(256) void modnorm_k(float* __restrict__ x1,
                                                 const bf16* __restrict__ mod, // [NTOK][2048] = shift|scale
                                                 const float* __restrict__ w,
                                                 bf16* __restrict__ h2) {
    int t = blockIdx.x, tid = threadIdx.x;
    float xs[4], ss = 0.f;
#pragma unroll
    for (int i = 0; i < 4; ++i) {
        int c = tid + i * 256;
        float sh = b2f(mod[(size_t)t * 2048 + c]);
        float sc = b2f(mod[(size_t)t * 2048 + 1024 + c]);
        float v = x1[(size_t)t * D_ + c] * (1.f + sc) + sh;
        xs[i] = v; ss += v * v;
        x1[(size_t)t * D_ + c] = v;
    }
    __shared__ float red[4];
#pragma unroll
    for (int off = 32; off > 0; off >>= 1) ss += __shfl_xor(ss, off, 64);
    if ((tid & 63) == 0) red[tid >> 6] = ss;
    __syncthreads();
    ss = red[0] + red[1] + red[2] + red[3];
    float inv = rsqrtf(ss * (1.f / D_) + 1e-6f);
#pragma unroll
    for (int i = 0; i < 4; ++i) {
        int c = tid + i * 256;
        h2[(size_t)t * D_ + c] = f2b(xs[i] * inv * w[c]);
    }
}

// ------------- ae1: [NTOK,16] @ [16,1024] + b, SiLU (fp32 in, bf16 out) -----
__global__ __launch_bounds__(256) void ae1_k(const float* __restrict__ actions,
                                             const float* __restrict__ w,
                                             const float* __restrict__ b,
                                             bf16* __restrict__ out) {
    int t = blockIdx.x, tid = threadIdx.x;
    float av[16];
#pragma unroll
    for (int a = 0; a < 16; ++a) av[a] = actions[(size_t)t * 16 + a];
#pragma unroll
    for (int i = 0; i < 4; ++i) {
        int n = tid + i * 256;
        float acc = b[n];
#pragma unroll
        for (int a = 0; a < 16; ++a) acc += av[a] * w[a * D_ + n];
        out[(size_t)t * D_ + n] = f2b(acc / (1.f + expf(-acc)));
    }
}

// ---- weight prep: fp32 W[K][N] (row stride ldw) -> bf16 WT[N][K], fused -----
struct WD { const float* src; bf16* dst; int K, N, ldw, tiles; };
struct WPack { WD d[8]; };
__global__ __launch_bounds__(256) void wprep_k(WPack p) {
    int bid = blockIdx.x;
    int mi = 0, cum = 0;
#pragma unroll
    for (mi = 0; mi < 8; ++mi) {
        if (bid < cum + p.d[mi].tiles) break;
        cum += p.d[mi].tiles;
    }
    if (mi >= 8) return;
    WD w = p.d[mi];
    int local = bid - cum;
    int tilesK = w.K >> 6;
    int tk = local % tilesK, tn = local / tilesK;
    int k0 = tk * 64, n0 = tn * 64;
    __shared__ short Tt[64 * 72];   // [n][k]
    int t = threadIdx.x;
    int row = t >> 2, seg = t & 3;
    const float* sp = w.src + (size_t)(k0 + row) * w.ldw + n0 + seg * 16;
#pragma unroll
    for (int q = 0; q < 4; ++q) {
        float4_ f = *(const float4_*)(sp + q * 4);
#pragma unroll
        for (int j = 0; j < 4; ++j) Tt[(seg * 16 + q * 4 + j) * 72 + row] = (short)f2s(f[j]);
    }
    __syncthreads();
    bf16* dp = w.dst + (size_t)(n0 + row) * w.K + k0 + seg * 16;
    *(short8*)dp       = *(const short8*)&Tt[row * 72 + seg * 16];
    *(short8*)(dp + 8) = *(const short8*)&Tt[row * 72 + seg * 16 + 8];
}

// ---- concat q_b|k_b|v_b -> biasQKV[3072] ------------------------------------
__global__ __launch_bounds__(256) void bcat_k(const float* __restrict__ qb,
                                              const float* __restrict__ kb,
                                              const float* __restrict__ vb,
                                              float* __restrict__ dst) {
    int i = blockIdx.x * 256 + threadIdx.x;   // grid 12*256 = 3072
    const float* s = (i < 1024) ? qb : (i < 2048) ? kb : vb;
    dst[i] = s[i & 1023];
}

// --------- MFMA GEMM 128x128: C = A[M,K](bf16) @ WT[N,K](bf16) ---------------
// ACT: 0 none, 1 SiLU, 2 GELU(exact). res added after ACT. ldo = out/res stride.
// QKN: fused per-head RMSNorm (HD=64) on cols<2048 (packed QKV output).
// VOUT: cols>=2048 (the V third) are written TRANSPOSED to vt[B*H][hd=64][T].
template <int ACT, int QKN, int VOUT, typename ResT, typename OutT>
__global__ __launch_bounds__(256) void gemm_k(const bf16* __restrict__ A,
                                              const bf16* __restrict__ Bt,
                                              const float* __restrict__ bias,
                                              const ResT* __restrict__ res,
                                              OutT* __restrict__ out,
                                              int M, int N, int K, int ldo,
                                              const float* __restrict__ qn_w,
                                              const float* __restrict__ kn_w,
                                              bf16* __restrict__ vt) {
    __shared__ __align__(16) short As[128 * 64];
    __shared__ __align__(16) short Bs[128 * 64];
    const int tid = threadIdx.x;
    const int bm = blockIdx.y * 128, bn = blockIdx.x * 128;
    const int wave = tid >> 6, lane = tid & 63;
    const int wm = (wave & 1) * 64, wn = (wave >> 1) * 64;
    const int l15 = lane & 15, quad = lane >> 4;
    const int lrow = lane >> 3, lseg = (lane & 7) * 8;
    float4_ acc[4][4] = {};

    for (int k0 = 0; k0 < K; k0 += 64) {
#pragma unroll
        for (int it = 0; it < 4; ++it) {
            int r = it * 32 + wave * 8;
            gl_lds16((const short*)A + (size_t)(bm + r + lrow) * K + k0 + lseg, &As[r * 64]);
            gl_lds16((const short*)Bt + (size_t)(bn + r + lrow) * K + k0 + lseg, &Bs[r * 64]);
        }
        __syncthreads();
#pragma unroll
        for (int kk = 0; kk < 64; kk += 32) {
            short8 af[4], bfr[4];
#pragma unroll
            for (int i = 0; i < 4; ++i)
                af[i] = *(const short8*)&As[(wm + i * 16 + l15) * 64 + kk + quad * 8];
#pragma unroll
            for (int j = 0; j < 4; ++j)
                bfr[j] = *(const short8*)&Bs[(wn + j * 16 + l15) * 64 + kk + quad * 8];
#pragma unroll
            for (int i = 0; i < 4; ++i)
#pragma unroll
                for (int j = 0; j < 4; ++j)
                    acc[i][j] = __builtin_amdgcn_mfma_f32_16x16x32_bf16(af[i], bfr[j], acc[i][j], 0, 0, 0);
        }
        __syncthreads();
    }

    int seg = (bn + wn) >> 10;               // 0=q, 1=k, >=2 = v
    float nwv[4];
    if (QKN && seg < 2) {
        const float* nw = seg ? kn_w : qn_w;
#pragma unroll
        for (int j = 0; j < 4; ++j) nwv[j] = nw[j * 16 + l15];
    }

#pragma unroll
    for (int i = 0; i < 4; ++i) {
        float vv[4][4];
#pragma unroll
        for (int j = 0; j < 4; ++j) {
            float bv = bias[bn + wn + j * 16 + l15];
#pragma unroll
            for (int r = 0; r < 4; ++r) vv[j][r] = acc[i][j][r] + bv;
        }
        if (QKN && seg < 2) {
#pragma unroll
            for (int r = 0; r < 4; ++r) {
                float ss = vv[0][r] * vv[0][r] + vv[1][r] * vv[1][r]
                         + vv[2][r] * vv[2][r] + vv[3][r] * vv[3][r];
#pragma unroll
                for (int off = 8; off > 0; off >>= 1) ss += __shfl_xor(ss, off, 16);
                float inv = rsqrtf(ss * (1.f / 64.f) + 1e-6f);
#pragma unroll
                for (int j = 0; j < 4; ++j) vv[j][r] *= inv * nwv[j];
            }
        }
        if (VOUT && seg >= 2) {
            // write V transposed: vt[(b*16+h)*64+hd][t], t = row, 4 consecutive t
#pragma unroll
            for (int j = 0; j < 4; ++j) {
                int col = bn + wn + j * 16 + l15 - 2048;
                int hh = col >> 6, hd = col & 63;
                int row0 = bm + wm + i * 16 + quad * 4;
                int bb = row0 >> 11, t0 = row0 & 2047;
                ushort4_ u = { f2s(vv[j][0]), f2s(vv[j][1]), f2s(vv[j][2]), f2s(vv[j][3]) };
                *(ushort4_*)((unsigned short*)vt + ((size_t)((bb * 16 + hh) * 64 + hd)) * 2048 + t0) = u;
            }
        } else {
#pragma unroll
            for (int j = 0; j < 4; ++j) {
                int col = bn + wn + j * 16 + l15;
#pragma unroll
                for (int r = 0; r < 4; ++r) {
                    int row = bm + wm + i * 16 + quad * 4 + r;
                    float v = vv[j][r];
                    if (ACT == 1) v = v / (1.f + expf(-v));
                    else if (ACT == 2) v = 0.5f * v * (1.f + erff(v * 0.70710678118654752f));
                    if (res) v += to_f(res[(size_t)row * ldo + col]);
                    store_o(&out[(size_t)row * ldo + col], v);
                }
            }
        }
    }
}

// --------- MFMA GEMM 64x128 tile: for N=1024 GEMMs (512 blocks = 2/CU) -------
template <int ACT, typename ResT, typename OutT>
__global__ __launch_bounds__(256) void gemm64_k(const bf16* __restrict__ A,
                                                const bf16* __restrict__ Bt,
                                                const float* __restrict__ bias,
                                                const ResT* __restrict__ res,
                                                OutT* __restrict__ out,
                                                int M, int N, int K) {
    __shared__ __align__(16) short As[64 * 64];
    __shared__ __align__(16) short Bs[128 * 64];
    const int tid = threadIdx.x;
    const int bm = blockIdx.y * 64, bn = blockIdx.x * 128;
    const int wave = tid >> 6, lane = tid & 63;
    const int wm = (wave & 1) * 32, wn = (wave >> 1) * 64;
    const int l15 = lane & 15, quad = lane >> 4;
    const int lrow = lane >> 3, lseg = (lane & 7) * 8;
    float4_ acc[2][4] = {};

    for (int k0 = 0; k0 < K; k0 += 64) {
#pragma unroll
        for (int it = 0; it < 2; ++it) {
            int r = wave * 16 + it * 8;
            gl_lds16((const short*)A + (size_t)(bm + r + lrow) * K + k0 + lseg, &As[r * 64]);
        }
#pragma unroll
        for (int it = 0; it < 4; ++it) {
            int r = it * 32 + wave * 8;
            gl_lds16((const short*)Bt + (size_t)(bn + r + lrow) * K + k0 + lseg, &Bs[r * 64]);
        }
        __syncthreads();
#pragma unroll
        for (int kk = 0; kk < 64; kk += 32) {
            short8 af[2], bfr[4];
#pragma unroll
            for (int i = 0; i < 2; ++i)
                af[i] = *(const short8*)&As[(wm + i * 16 + l15) * 64 + kk + quad * 8];
#pragma unroll
            for (int j = 0; j < 4; ++j)
                bfr[j] = *(const short8*)&Bs[(wn + j * 16 + l15) * 64 + kk + quad * 8];
#pragma unroll
            for (int i = 0; i < 2; ++i)
#pragma unroll
                for (int j = 0; j < 4; ++j)
                    acc[i][j] = __builtin_amdgcn_mfma_f32_16x16x32_bf16(af[i], bfr[j], acc[i][j], 0, 0, 0);
        }
        __syncthreads();
    }

#pragma unroll
    for (int i = 0; i < 2; ++i)
#pragma unroll
        for (int j = 0; j < 4; ++j) {
            int col = bn + wn + j * 16 + l15;
            float bv = bias[col];
#pragma unroll
            for (int r = 0; r < 4; ++r) {
                int row = bm + wm + i * 16 + quad * 4 + r;
                float v = acc[i][j][r] + bv;
                if (ACT == 1) v = v / (1.f + expf(-v));
                else if (ACT == 2) v = 0.5f * v * (1.f + erff(v * 0.70710678118654752f));
                if (res) v += to_f(res[(size_t)row * N + col]);
                store_o(&out[(size_t)row * N + col], v);
            }
        }
}

// -------------- flash attention, causal, HD=64, BARRIER-FREE -----------------
// One wave per block (64 threads), q-tile 16, KV tile 64, LPT order.
// QK packed [NTOK][2048]; V pre-transposed VT[B*H][hd=64][T]. K and V^T
// fragments load DIRECTLY from global (coalesced 16B/lane) -> no staging, no
// __syncthreads anywhere. No-max softmax (qk-RMSNorm bounds |s|<=8.1), l
// accumulated per-lane and reduced once at the end.
__global__ __launch_bounds__(64) void attn_k(const bf16* __restrict__ QK,
                                             const bf16* __restrict__ VT,
                                             bf16* __restrict__ O) {
    __shared__ __align__(16) short Ps[16 * 72];     // [q][kv], one wave
    const int bh = blockIdx.y, b = bh >> 4, h = bh & 15;
    const int q0 = T_ - 16 * (blockIdx.x + 1);      // longest-first
    const int lane = threadIdx.x;
    const int l15 = lane & 15, quad = lane >> 4;
    const short* Qp = (const short*)QK + (size_t)b * T_ * 2048 + h * 64;
    const short* Kp = Qp + 1024;
    const short* Vp = (const short*)VT + (size_t)(b * 16 + h) * 64 * 2048;  // [hd][t]

    const int qrow = q0 + l15;
    short8 qf0 = *(const short8*)(Qp + (size_t)qrow * 2048 + quad * 8);
    short8 qf1 = *(const short8*)(Qp + (size_t)qrow * 2048 + 32 + quad * 8);

    float4_ oacc[4] = {};
    float l_r[4] = {0.f, 0.f, 0.f, 0.f};
    const int nit = q0 / 64 + 1;

    for (int it = 0; it < nit; ++it) {
        const int kv0 = it * 64;

        // QK^T: K fragments direct from global
        float4_ s[4];
#pragma unroll
        for (int c = 0; c < 4; ++c) {
            const short* kp = Kp + (size_t)(kv0 + c * 16 + l15) * 2048 + quad * 8;
            short8 kb0 = *(const short8*)kp;
            short8 kb1 = *(const short8*)(kp + 32);
            float4_ sc = {};
            sc = __builtin_amdgcn_mfma_f32_16x16x32_bf16(qf0, kb0, sc, 0, 0, 0);
            sc = __builtin_amdgcn_mfma_f32_16x16x32_bf16(qf1, kb1, sc, 0, 0, 0);
            s[c] = sc;
        }

        // mask + exp + per-lane l accumulate
#pragma unroll
        for (int r = 0; r < 4; ++r) {
            int qr = q0 + quad * 4 + r;
#pragma unroll
            for (int c = 0; c < 4; ++c) {
                int kvi = kv0 + c * 16 + l15;
                float val = (kvi > qr) ? NEG_SENT : s[c][r] * 0.125f;
                float p = __expf(val);           // exp(NEG_SENT) == 0
                s[c][r] = p;
                l_r[r] += p;
            }
        }

        // P: C/D -> A layout via LDS (single wave: DS in-order, no barrier)
#pragma unroll
        for (int c = 0; c < 4; ++c)
#pragma unroll
            for (int r = 0; r < 4; ++r)
                Ps[(quad * 4 + r) * 72 + c * 16 + l15] = (short)f2s(s[c][r]);

#pragma unroll
        for (int kk = 0; kk < 64; kk += 32) {
            short8 pf = *(const short8*)&Ps[l15 * 72 + kk + quad * 8];
#pragma unroll
            for (int d = 0; d < 4; ++d) {
                short8 vf = *(const short8*)(Vp + (size_t)(d * 16 + l15) * 2048 + kv0 + kk + quad * 8);
                oacc[d] = __builtin_amdgcn_mfma_f32_16x16x32_bf16(pf, vf, oacc[d], 0, 0, 0);
            }
        }
    }

    // deferred l reduction over the 16-lane q-group
    float linv[4];
#pragma unroll
    for (int r = 0; r < 4; ++r) {
        float l = l_r[r];
#pragma unroll
        for (int off = 8; off > 0; off >>= 1) l += __shfl_xor(l, off, 16);
        linv[r] = 1.f / l;                       // diagonal term guarantees l > 0
    }
#pragma unroll
    for (int d = 0; d < 4; ++d)
#pragma unroll
        for (int r = 0; r < 4; ++r) {
            int qr = q0 + quad * 4 + r;
            O[(size_t)(b * T_ + qr) * D_ + h * 64 + d * 16 + l15] = f2b(oacc[d][r] * linv[r]);
        }
}

// ---------------------------------------------------------------------------
// Workspace (~70.1 MB):
//   Ah[0,8) ; QKp[8,24) ([NTOK][2048]) ; VT[24,32) ([B*H][64][T]) ; AO[32,40)
//   after attn+o-proj: AE1[8,16) AES[16,24) MOD[24,40) ; M1G[8,40) after modnorm
//   weights [40,70): WTqkv 40 WTo 46 WTae2 48 WTmod 50 WTm1 54 WTm2 62
//   biasQKV at 70MB. X1 (fp32 residual) lives in d_out.
extern "C" void kernel_launch(void* const* d_in, const int* in_sizes, int n_in,
                              void* d_out, int out_size, void* d_ws, size_t ws_size,
                              hipStream_t stream) {
    const float* x     = (const float*)d_in[0];
    const float* acts  = (const float*)d_in[1];
    const float* n1_w  = (const float*)d_in[2];
    const float* n2_w  = (const float*)d_in[3];
    const float* q_w   = (const float*)d_in[4];
    const float* q_b   = (const float*)d_in[5];
    const float* k_w   = (const float*)d_in[6];
    const float* k_b   = (const float*)d_in[7];
    const float* v_w   = (const float*)d_in[8];
    const float* v_b   = (const float*)d_in[9];
    const float* qn_w  = (const float*)d_in[10];
    const float* kn_w  = (const float*)d_in[11];
    const float* o_w   = (const float*)d_in[12];
    const float* o_b   = (const float*)d_in[13];
    const float* ae1_w = (const float*)d_in[14];
    const float* ae1_b = (const float*)d_in[15];
    const float* ae2_w = (const float*)d_in[16];
    const float* ae2_b = (const float*)d_in[17];
    const float* mod_w = (const float*)d_in[18];
    const float* mod_b = (const float*)d_in[19];
    const float* m1_w  = (const float*)d_in[20];
    const float* m1_b  = (const float*)d_in[21];
    const float* m2_w  = (const float*)d_in[22];
    const float* m2_b  = (const float*)d_in[23];
    float* out = (float*)d_out;

    char* ws = (char*)d_ws;
    const size_t MB = 1ull << 20;
    bf16*  Ah   = (bf16*)(ws + 0);
    bf16*  QKp  = (bf16*)(ws + 8 * MB);    // [NTOK][2048]
    bf16*  VT   = (bf16*)(ws + 24 * MB);   // [B*H][64][T]
    bf16*  AO   = (bf16*)(ws + 32 * MB);
    bf16*  AE1  = (bf16*)(ws + 8 * MB);
    bf16*  AES  = (bf16*)(ws + 16 * MB);
    bf16*  MOD  = (bf16*)(ws + 24 * MB);
    bf16*  M1G  = (bf16*)(ws + 8 * MB);
    float* X1   = out;

    bf16* WTqkv = (bf16*)(ws + 40 * MB);   // q|k|v contiguous -> [3072][1024]
    bf16* WTo   = (bf16*)(ws + 46 * MB);
    bf16* WTae2 = (bf16*)(ws + 48 * MB);
    bf16* WTmod = (bf16*)(ws + 50 * MB);   // [2048][1024]
    bf16* WTm1  = (bf16*)(ws + 54 * MB);   // [4096][1024]
    bf16* WTm2  = (bf16*)(ws + 62 * MB);   // [1024][4096]
    float* biasQKV = (float*)(ws + 70 * MB);

    dim3 blk(256);

    WPack p;
    p.d[0] = { q_w,   WTqkv,                1024, 1024, 1024, 256 };
    p.d[1] = { k_w,   WTqkv + 1024 * 1024,  1024, 1024, 1024, 256 };
    p.d[2] = { v_w,   WTqkv + 2048 * 1024,  1024, 1024, 1024, 256 };
    p.d[3] = { o_w,   WTo,   1024, 1024, 1024, 256 };
    p.d[4] = { ae2_w, WTae2, 1024, 1024, 1024, 256 };
    p.d[5] = { mod_w, WTmod, 1024, 2048, 4096, 512 };
    p.d[6] = { m1_w,  WTm1,  1024, 4096, 4096, 1024 };
    p.d[7] = { m2_w,  WTm2,  4096, 1024, 1024, 1024 };
    wprep_k<<<3840, blk, 0, stream>>>(p);
    bcat_k<<<12, blk, 0, stream>>>(q_b, k_b, v_b, biasQKV);

    rmsnorm_k<<<NTOK, blk, 0, stream>>>(x, n1_w, Ah);
    gemm_k<0, 1, 1, float, bf16><<<dim3(24, 32), blk, 0, stream>>>(Ah, WTqkv, biasQKV, (const float*)nullptr, QKp, NTOK, 3072, 1024, 2048, qn_w, kn_w, VT);
    attn_k<<<dim3(T_ / 16, B_ * H_), dim3(64), 0, stream>>>(QKp, VT, AO);
    gemm64_k<0, float, float><<<dim3(8, 64), blk, 0, stream>>>(AO, WTo, o_b, x, X1, NTOK, 1024, 1024);
    ae1_k<<<NTOK, blk, 0, stream>>>(acts, ae1_w, ae1_b, AE1);
    gemm64_k<1, float, bf16><<<dim3(8, 64), blk, 0, stream>>>(AE1, WTae2, ae2_b, (const float*)nullptr, AES, NTOK, 1024, 1024);
    gemm_k<0, 0, 0, float, bf16><<<dim3(16, 32), blk, 0, stream>>>(AES, WTmod, mod_b, (const float*)nullptr, MOD, NTOK, 2048, 1024, 2048, nullptr, nullptr, nullptr);
    modnorm_k<<<NTOK, blk, 0, stream>>>(X1, MOD, n2_w, Ah);
    gemm_k<2, 0, 0, float, bf16><<<dim3(32, 32), blk, 0, stream>>>(Ah, WTm1, m1_b, (const float*)nullptr, M1G, NTOK, 4096, 1024, 4096, nullptr, nullptr, nullptr);
    gemm64_k<0, float, float><<<dim3(8, 64), blk, 0, stream>>>(M1G, WTm2, m2_b, X1, out, NTOK, 1024, 4096);
}